// Round 1
// baseline (103.143 us; speedup 1.0000x reference)
//
#include <hip/hip_runtime.h>

// ---------------------------------------------------------------------------
// y = x @ Q^T where Q = H_0 H_1 ... H_{N-1}, H_n = I - 2 v_n v_n^T/(v_n.v_n+eps)
// S=256, N=258, B=65536.
// Phase 1: c2[n] = 2/(v_n.v_n + 1e-16)
// Phase 2: Q rows (independent chains), output bf16 Q row-major [j][k]
// Phase 3: GEMM y[b][j] = sum_k x[b][k] Q[j][k]  (BT layout, bf16 MFMA)
// ---------------------------------------------------------------------------

#define GLOAD_LDS16(g, l)                                                      \
  __builtin_amdgcn_global_load_lds(                                            \
      (const __attribute__((address_space(1))) void*)(g),                      \
      (__attribute__((address_space(3))) void*)(l), 16, 0, 0)

typedef __attribute__((ext_vector_type(8))) short bf16x8;
typedef __attribute__((ext_vector_type(4))) float f32x4;

__device__ __forceinline__ unsigned short f2bf_rne(float f) {
  unsigned u = __builtin_bit_cast(unsigned, f);
  return (unsigned short)((u + 0x7fffu + ((u >> 16) & 1u)) >> 16);
}

// ---------------- Phase 1: inner products -> c2 ----------------------------
__global__ void hh_inner(const float* __restrict__ vecs, float* __restrict__ c2) {
  const int n = blockIdx.x;   // 0..257
  const int l = threadIdx.x;  // 0..63
  const float* v = vecs + n * 256;
  float p = 0.f;
#pragma unroll
  for (int i = 0; i < 4; ++i) {
    float t = v[l + 64 * i];
    p += t * t;
  }
#pragma unroll
  for (int off = 32; off; off >>= 1) p += __shfl_xor(p, off);
  if (l == 0) c2[n] = 2.0f / (p + 1e-16f);
}

// ---------------- Phase 2: Q rows ------------------------------------------
// One wave per row. Lane l owns columns {l, l+64, l+128, l+192}.
// row <- row - c2[n] * (row . v_n) * v_n, n = 0..257 (left-to-right product).
__global__ void hh_qrows(const float* __restrict__ vecs,
                         const float* __restrict__ c2,
                         unsigned short* __restrict__ Qb) {
  const int row = blockIdx.x;  // 0..255
  const int l = threadIdx.x;   // 0..63
  float q0 = (l == row) ? 1.f : 0.f;
  float q1 = (l + 64 == row) ? 1.f : 0.f;
  float q2 = (l + 128 == row) ? 1.f : 0.f;
  float q3 = (l + 192 == row) ? 1.f : 0.f;
  // prefetched v / c for current step
  float a0 = vecs[l], a1 = vecs[l + 64], a2 = vecs[l + 128], a3 = vecs[l + 192];
  float cc = c2[0];
  for (int n = 0; n < 258; ++n) {
    float b0 = 0.f, b1 = 0.f, b2 = 0.f, b3 = 0.f, cn = 0.f;
    if (n < 257) {  // prefetch next step's data before the reduce chain
      const float* v = vecs + (n + 1) * 256;
      b0 = v[l]; b1 = v[l + 64]; b2 = v[l + 128]; b3 = v[l + 192];
      cn = c2[n + 1];
    }
    float p = q0 * a0 + q1 * a1 + q2 * a2 + q3 * a3;
#pragma unroll
    for (int off = 32; off; off >>= 1) p += __shfl_xor(p, off);
    const float s = cc * p;
    q0 -= s * a0; q1 -= s * a1; q2 -= s * a2; q3 -= s * a3;
    a0 = b0; a1 = b1; a2 = b2; a3 = b3; cc = cn;
  }
  Qb[row * 256 + l] = f2bf_rne(q0);
  Qb[row * 256 + l + 64] = f2bf_rne(q1);
  Qb[row * 256 + l + 128] = f2bf_rne(q2);
  Qb[row * 256 + l + 192] = f2bf_rne(q3);
}

// ---------------- Phase 3: GEMM --------------------------------------------
// C[M=65536][256] = A[M][K=256](f32, cvt->bf16) * B[N=256][K=256](bf16, BT)
// Block: BM=128, BN=256 (full N -> x read exactly once), BK=32, 512 thr (8 waves).
// Wave grid 2x4; per-wave 64x64 = 4x4 frags of 16x16x32.
// LDS 64KB: A dbuf [128][32] f32 @0/16K, B dbuf [256][32] bf16 @32K/48K.
// XOR-swizzled staging (swizzle applied to the GLOBAL source address, LDS dest
// linear as required by global_load_lds) to avoid bank conflicts on ds_read.
__launch_bounds__(512)
__global__ void hh_gemm(const float* __restrict__ X,
                        const unsigned short* __restrict__ Qb,
                        float* __restrict__ Y) {
  __shared__ __align__(128) char lds[65536];
  const int tid = threadIdx.x;
  const int lane = tid & 63;
  const int wid = tid >> 6;
  const int wm = wid >> 2;  // 0..1
  const int wn = wid & 3;   // 0..3
  const int fr = lane & 15; // fragment row (A-row / B-col)
  const int fg = lane >> 4; // k-group
  const long bm0 = (long)blockIdx.x * 128;

  auto stage = [&](int buf, int kt) {
    // A tile [128][32] f32: 8 segs of 16B per row; phys seg = seg ^ (row&7)
#pragma unroll
    for (int r2 = 0; r2 < 2; ++r2) {
      int slot = r2 * 512 + tid;
      int row = slot >> 3, seg = slot & 7;
      int ps = seg ^ (row & 7);
      GLOAD_LDS16(X + (bm0 + row) * 256 + kt * 32 + ps * 4,
                  lds + buf * 16384 + slot * 16);
    }
    // B tile [256][32] bf16: 4 segs of 16B per row; phys seg = seg ^ (row&3)
#pragma unroll
    for (int r2 = 0; r2 < 2; ++r2) {
      int slot = r2 * 512 + tid;
      int row = slot >> 2, seg = slot & 3;
      int ps = seg ^ (row & 3);
      GLOAD_LDS16(Qb + row * 256 + kt * 32 + ps * 8,
                  lds + 32768 + buf * 16384 + slot * 16);
    }
  };

  f32x4 acc[4][4];
#pragma unroll
  for (int m = 0; m < 4; ++m)
#pragma unroll
    for (int n = 0; n < 4; ++n) acc[m][n] = (f32x4){0.f, 0.f, 0.f, 0.f};

  stage(0, 0);
  __syncthreads();

  for (int kt = 0; kt < 8; ++kt) {
    const int cur = kt & 1;
    if (kt < 7) stage(cur ^ 1, kt + 1);

    bf16x8 aF[4], bF[4];
#pragma unroll
    for (int m = 0; m < 4; ++m) {
      int row = wm * 64 + m * 16 + fr;  // 0..127
      int s0 = (2 * fg) ^ (row & 7);
      int s1 = (2 * fg + 1) ^ (row & 7);
      const f32x4 x0 = *(const f32x4*)(lds + cur * 16384 + row * 128 + s0 * 16);
      const f32x4 x1 = *(const f32x4*)(lds + cur * 16384 + row * 128 + s1 * 16);
      bf16x8 t;
      t[0] = (short)f2bf_rne(x0[0]);
      t[1] = (short)f2bf_rne(x0[1]);
      t[2] = (short)f2bf_rne(x0[2]);
      t[3] = (short)f2bf_rne(x0[3]);
      t[4] = (short)f2bf_rne(x1[0]);
      t[5] = (short)f2bf_rne(x1[1]);
      t[6] = (short)f2bf_rne(x1[2]);
      t[7] = (short)f2bf_rne(x1[3]);
      aF[m] = t;
    }
#pragma unroll
    for (int n = 0; n < 4; ++n) {
      int row = wn * 64 + n * 16 + fr;  // 0..255
      int ps = fg ^ (row & 3);
      bF[n] = *(const bf16x8*)(lds + 32768 + cur * 16384 + row * 64 + ps * 16);
    }
#pragma unroll
    for (int m = 0; m < 4; ++m)
#pragma unroll
      for (int n = 0; n < 4; ++n)
        acc[m][n] =
            __builtin_amdgcn_mfma_f32_16x16x32_bf16(aF[m], bF[n], acc[m][n], 0, 0, 0);
    __syncthreads();
  }

  // Epilogue: C/D layout col = lane&15, row = (lane>>4)*4 + reg
#pragma unroll
  for (int m = 0; m < 4; ++m)
#pragma unroll
    for (int n = 0; n < 4; ++n)
#pragma unroll
      for (int r = 0; r < 4; ++r) {
        long grow = bm0 + wm * 64 + m * 16 + fg * 4 + r;
        int gcol = wn * 64 + n * 16 + fr;
        Y[grow * 256 + gcol] = acc[m][n][r];
      }
}

// ---------------------------------------------------------------------------
extern "C" void kernel_launch(void* const* d_in, const int* in_sizes, int n_in,
                              void* d_out, int out_size, void* d_ws, size_t ws_size,
                              hipStream_t stream) {
  const float* x = (const float*)d_in[0];      // [65536][256] f32
  const float* vecs = (const float*)d_in[1];   // [258][256] f32
  float* y = (float*)d_out;                    // [65536][256] f32

  float* c2 = (float*)d_ws;                                    // 258 f32
  unsigned short* Qb = (unsigned short*)((char*)d_ws + 4096);  // 256x256 bf16

  hh_inner<<<258, 64, 0, stream>>>(vecs, c2);
  hh_qrows<<<256, 64, 0, stream>>>(vecs, c2, Qb);
  hh_gemm<<<512, 512, 0, stream>>>(x, Qb, y);
}

// Round 3
// 76.504 us; speedup vs baseline: 1.3482x; 1.3482x over previous
//
#include <hip/hip_runtime.h>

// ---------------------------------------------------------------------------
// y = x @ Q^T where Q = H_0 H_1 ... H_{N-1}, H_n = I - 2 v_n v_n^T/(v_n.v_n+eps)
// S=256, N=258, B=65536.
// Phase 1: c2[n] = 2/(v_n.v_n + 1e-16)
// Phase 2: Q rows (independent chains), 16 lanes/row, DPP-only reduce
// Phase 3: GEMM y[b][j] = sum_k x[b][k] Q[j][k]  (BT layout, bf16 MFMA)
// ---------------------------------------------------------------------------

#define GLOAD_LDS16(g, l)                                                      \
  __builtin_amdgcn_global_load_lds(                                            \
      (const __attribute__((address_space(1))) void*)(g),                      \
      (__attribute__((address_space(3))) void*)(l), 16, 0, 0)

typedef __attribute__((ext_vector_type(8))) short bf16x8;
typedef __attribute__((ext_vector_type(4))) float f32x4;

__device__ __forceinline__ unsigned short f2bf_rne(float f) {
  unsigned u = __builtin_bit_cast(unsigned, f);
  return (unsigned short)((u + 0x7fffu + ((u >> 16) & 1u)) >> 16);
}

// DPP-shuffled add: v + dpp(v). CTRL: 0xB1=quad xor1, 0x4E=quad xor2,
// 0x124=row_ror:4, 0x128=row_ror:8. Pure VALU latency, no LDS.
template <int CTRL>
__device__ __forceinline__ float dpp_add(float v) {
  int t = __builtin_amdgcn_update_dpp(0, __builtin_bit_cast(int, v), CTRL, 0xF,
                                      0xF, true);
  return v + __builtin_bit_cast(float, t);
}

// ---------------- Phase 1: inner products -> c2 ----------------------------
__global__ void hh_inner(const float* __restrict__ vecs, float* __restrict__ c2) {
  const int n = blockIdx.x;   // 0..257
  const int l = threadIdx.x;  // 0..63
  const float* v = vecs + n * 256;
  float p = 0.f;
#pragma unroll
  for (int i = 0; i < 4; ++i) {
    float t = v[l + 64 * i];
    p += t * t;
  }
#pragma unroll
  for (int off = 32; off; off >>= 1) p += __shfl_xor(p, off);
  if (l == 0) c2[n] = 2.0f / (p + 1e-16f);
}

// ---------------- Phase 2: Q rows ------------------------------------------
// 64 blocks x 64 threads. Lane l: row-in-block r=l>>4, col-group c=l&15.
// Each lane owns 16 contiguous columns of one Q row. The per-step dot-reduce
// stays inside a 16-lane DPP row (quad_perm + row_ror) -> no LDS ops on the
// critical chain. v is prefetched 2 steps deep (ping-pong A/B buffer pairs).
__global__ void hh_qrows(const float* __restrict__ vecs,
                         const float* __restrict__ c2,
                         unsigned short* __restrict__ Qb) {
  const int l = threadIdx.x;
  const int r = l >> 4;
  const int c = l & 15;
  const int row = blockIdx.x * 4 + r;
  const int col0 = c * 16;

  float q[16];
#pragma unroll
  for (int i = 0; i < 16; ++i) q[i] = (col0 + i == row) ? 1.f : 0.f;

  auto load16 = [&](float(&d)[16], int n) {
    const float4* v = (const float4*)(vecs + (long)n * 256 + col0);
#pragma unroll
    for (int i = 0; i < 4; ++i) {
      float4 t = v[i];
      d[4 * i] = t.x; d[4 * i + 1] = t.y; d[4 * i + 2] = t.z; d[4 * i + 3] = t.w;
    }
  };

  auto step = [&](const float(&a)[16], float cc) {
    float p0 = 0.f, p1 = 0.f, p2 = 0.f, p3 = 0.f;
#pragma unroll
    for (int i = 0; i < 4; ++i) {
      p0 = fmaf(q[i], a[i], p0);
      p1 = fmaf(q[4 + i], a[4 + i], p1);
      p2 = fmaf(q[8 + i], a[8 + i], p2);
      p3 = fmaf(q[12 + i], a[12 + i], p3);
    }
    float p = (p0 + p1) + (p2 + p3);
    p = dpp_add<0xB1>(p);   // xor1 within quad
    p = dpp_add<0x4E>(p);   // xor2 within quad
    p = dpp_add<0x124>(p);  // row_ror:4  (quad-sum rotate)
    p = dpp_add<0x128>(p);  // row_ror:8  -> full 16-lane sum in all lanes
    const float s = cc * p;
#pragma unroll
    for (int i = 0; i < 16; ++i) q[i] = fmaf(-s, a[i], q[i]);
  };

  float A0[16], A1[16], B0[16], B1[16];
  load16(A0, 0); load16(A1, 1); load16(B0, 2); load16(B1, 3);
  float cA0 = c2[0], cA1 = c2[1], cB0 = c2[2], cB1 = c2[3];

  for (int t = 0; t < 64; ++t) {
    const int s4 = 4 * t;
    step(A0, cA0);
    step(A1, cA1);
    const int n0 = min(s4 + 4, 257), n1 = min(s4 + 5, 257);
    load16(A0, n0); load16(A1, n1);
    cA0 = c2[n0]; cA1 = c2[n1];
    step(B0, cB0);
    step(B1, cB1);
    const int n2 = min(s4 + 6, 257), n3 = min(s4 + 7, 257);
    load16(B0, n2); load16(B1, n3);
    cB0 = c2[n2]; cB1 = c2[n3];
  }
  step(A0, cA0);  // step 256
  step(A1, cA1);  // step 257

#pragma unroll
  for (int i = 0; i < 16; ++i) Qb[row * 256 + col0 + i] = f2bf_rne(q[i]);
}

// ---------------- Phase 3: GEMM --------------------------------------------
// C[M=65536][256] = A[M][K=256](f32, cvt->bf16) * B[N=256][K=256](bf16, BT)
// Block: BM=128, BN=256 (full N -> x read exactly once), BK=32, 512 thr (8 waves).
// Wave grid 2x4; per-wave 64x64 = 4x4 frags of 16x16x32.
// LDS 64KB: A dbuf [128][32] f32 @0/16K, B dbuf [256][32] bf16 @32K/48K.
// XOR-swizzled staging (swizzle applied to the GLOBAL source address, LDS dest
// linear as required by global_load_lds) to avoid bank conflicts on ds_read.
__launch_bounds__(512)
__global__ void hh_gemm(const float* __restrict__ X,
                        const unsigned short* __restrict__ Qb,
                        float* __restrict__ Y) {
  __shared__ __align__(128) char lds[65536];
  const int tid = threadIdx.x;
  const int lane = tid & 63;
  const int wid = tid >> 6;
  const int wm = wid >> 2;  // 0..1
  const int wn = wid & 3;   // 0..3
  const int fr = lane & 15; // fragment row (A-row / B-col)
  const int fg = lane >> 4; // k-group
  const long bm0 = (long)blockIdx.x * 128;

  auto stage = [&](int buf, int kt) {
    // A tile [128][32] f32: 8 segs of 16B per row; phys seg = seg ^ (row&7)
#pragma unroll
    for (int r2 = 0; r2 < 2; ++r2) {
      int slot = r2 * 512 + tid;
      int row = slot >> 3, seg = slot & 7;
      int ps = seg ^ (row & 7);
      GLOAD_LDS16(X + (bm0 + row) * 256 + kt * 32 + ps * 4,
                  lds + buf * 16384 + slot * 16);
    }
    // B tile [256][32] bf16: 4 segs of 16B per row; phys seg = seg ^ (row&3)
#pragma unroll
    for (int r2 = 0; r2 < 2; ++r2) {
      int slot = r2 * 512 + tid;
      int row = slot >> 2, seg = slot & 3;
      int ps = seg ^ (row & 3);
      GLOAD_LDS16(Qb + row * 256 + kt * 32 + ps * 8,
                  lds + 32768 + buf * 16384 + slot * 16);
    }
  };

  f32x4 acc[4][4];
#pragma unroll
  for (int m = 0; m < 4; ++m)
#pragma unroll
    for (int n = 0; n < 4; ++n) acc[m][n] = (f32x4){0.f, 0.f, 0.f, 0.f};

  stage(0, 0);
  __syncthreads();

  for (int kt = 0; kt < 8; ++kt) {
    const int cur = kt & 1;
    if (kt < 7) stage(cur ^ 1, kt + 1);

    bf16x8 aF[4], bF[4];
#pragma unroll
    for (int m = 0; m < 4; ++m) {
      int row = wm * 64 + m * 16 + fr;  // 0..127
      int s0 = (2 * fg) ^ (row & 7);
      int s1 = (2 * fg + 1) ^ (row & 7);
      const f32x4 x0 = *(const f32x4*)(lds + cur * 16384 + row * 128 + s0 * 16);
      const f32x4 x1 = *(const f32x4*)(lds + cur * 16384 + row * 128 + s1 * 16);
      bf16x8 t;
      t[0] = (short)f2bf_rne(x0[0]);
      t[1] = (short)f2bf_rne(x0[1]);
      t[2] = (short)f2bf_rne(x0[2]);
      t[3] = (short)f2bf_rne(x0[3]);
      t[4] = (short)f2bf_rne(x1[0]);
      t[5] = (short)f2bf_rne(x1[1]);
      t[6] = (short)f2bf_rne(x1[2]);
      t[7] = (short)f2bf_rne(x1[3]);
      aF[m] = t;
    }
#pragma unroll
    for (int n = 0; n < 4; ++n) {
      int row = wn * 64 + n * 16 + fr;  // 0..255
      int ps = fg ^ (row & 3);
      bF[n] = *(const bf16x8*)(lds + 32768 + cur * 16384 + row * 64 + ps * 16);
    }
#pragma unroll
    for (int m = 0; m < 4; ++m)
#pragma unroll
      for (int n = 0; n < 4; ++n)
        acc[m][n] =
            __builtin_amdgcn_mfma_f32_16x16x32_bf16(aF[m], bF[n], acc[m][n], 0, 0, 0);
    __syncthreads();
  }

  // Epilogue: C/D layout col = lane&15, row = (lane>>4)*4 + reg
#pragma unroll
  for (int m = 0; m < 4; ++m)
#pragma unroll
    for (int n = 0; n < 4; ++n)
#pragma unroll
      for (int r = 0; r < 4; ++r) {
        long grow = bm0 + wm * 64 + m * 16 + fg * 4 + r;
        int gcol = wn * 64 + n * 16 + fr;
        Y[grow * 256 + gcol] = acc[m][n][r];
      }
}

// ---------------------------------------------------------------------------
extern "C" void kernel_launch(void* const* d_in, const int* in_sizes, int n_in,
                              void* d_out, int out_size, void* d_ws, size_t ws_size,
                              hipStream_t stream) {
  const float* x = (const float*)d_in[0];      // [65536][256] f32
  const float* vecs = (const float*)d_in[1];   // [258][256] f32
  float* y = (float*)d_out;                    // [65536][256] f32

  float* c2 = (float*)d_ws;                                    // 258 f32
  unsigned short* Qb = (unsigned short*)((char*)d_ws + 4096);  // 256x256 bf16

  hh_inner<<<258, 64, 0, stream>>>(vecs, c2);
  hh_qrows<<<64, 64, 0, stream>>>(vecs, c2, Qb);
  hh_gemm<<<512, 512, 0, stream>>>(x, Qb, y);
}